// Round 13
// baseline (39.774 us; speedup 1.0000x reference)
//
#include <hip/hip_runtime.h>

#define TOK_TOTAL 8192
#define DDIM 512
#define HDIM 256
#define ODIM 2
#define NHEADS 16
#define VOCAB 1024

typedef __attribute__((ext_vector_type(8))) short short8;
typedef __attribute__((ext_vector_type(4))) float f32x4;
typedef __attribute__((ext_vector_type(4))) unsigned short ushort4v;

__device__ inline ushort f2bf(float f) {           // RNE fp32->bf16
    uint u = __float_as_uint(f);
    uint r = (u + 0x7fffu + ((u >> 16) & 1u)) >> 16;
    return (ushort)r;
}
__device__ inline float bf2f(ushort h) { return __uint_as_float(((uint)h) << 16); }

// ---------------------------------------------------------- prep+route ----
// Blocks [0,384): W1/W2 fp32 -> single bf16(RNE) plane per (n,kc) in
//   LANE-MONOTONIC fragment order (wave B-frag load = one contiguous 1KB).
// Blocks [384,416): routing with LDS-atomic histogram prefix (atomics
//   pipeline the scan; ballot version serializes - r8 regression).
__global__ __launch_bounds__(256) void mth_prep_route(
    const float* __restrict__ W1, const float* __restrict__ W2,
    const int* __restrict__ tasks, const int* __restrict__ lut,
    ushort* __restrict__ W1h, ushort* __restrict__ W2h,
    int* __restrict__ counts, int* __restrict__ lists,
    float* __restrict__ out)
{
    const int b = blockIdx.x, t = threadIdx.x;

    if (b < 384) {                       // ---------------- W split ----------
        __shared__ float s[32][257];
        const float* src;
        ushort* dh;
        if (b < 256) {
            const int n = b >> 4, kc = b & 15;
            src = W1 + (size_t)(n * 16 + kc) * 8192;
            dh  = W1h + (size_t)(n * 16 + kc) * 8192;
        } else {
            const int b2 = b - 256, n = b2 >> 3, kc = b2 & 7;
            src = W2 + (size_t)(n * 8 + kc) * 8192;
            dh  = W2h + (size_t)(n * 8 + kc) * 8192;
        }
        #pragma unroll
        for (int i = 0; i < 8; ++i) {
            const int q = t + i * 256;
            const float4 f = ((const float4*)src)[q];
            const int k = q >> 6, c4 = (q & 63) * 4;
            s[k][c4] = f.x; s[k][c4 + 1] = f.y; s[k][c4 + 2] = f.z; s[k][c4 + 3] = f.w;
        }
        __syncthreads();
        #pragma unroll
        for (int i = 0; i < 4; ++i) {
            const int s8 = t + i * 256;          // short8 slot, monotonic
            const int lidx = s8 & 63;
            const int c = (s8 >> 6) * 16 + (lidx & 15);
            const int kw = (lidx >> 4) * 8;
            short8 hb;
            #pragma unroll
            for (int j = 0; j < 8; ++j) hb[j] = (short)f2bf(s[kw + j][c]);
            *(short8*)(dh + (size_t)s8 * 8) = hb;
        }
        return;
    }

    // ---------------- routing (atomic histogram prefix) ----------------
    const int i = b - 384;               // chunk 0..31
    __shared__ int hist[16];             // counts in chunks < i
    __shared__ int wcnt[4][16];          // per-wave counts in own chunk
    if (t < 16) hist[t] = 0;
    __syncthreads();
    for (int q = t; q < i * 256; q += 256) {
        const int task = tasks[q];
        const int h = (task >= 0 && task < VOCAB) ? lut[task] : -1;
        if (h >= 0) atomicAdd(&hist[h], 1);
    }
    const int tok = i * 256 + t;
    const int task = tasks[tok];
    const int h = (task >= 0 && task < VOCAB) ? lut[task] : -1;
    if (h < 0) {
        out[(size_t)tok * 2]     = 0.f;
        out[(size_t)tok * 2 + 1] = 0.f;
    }
    const int w = t >> 6, l = t & 63;
    const unsigned long long lt = (1ULL << l) - 1ULL;
    int pre = 0;
    #pragma unroll
    for (int n = 0; n < NHEADS; ++n) {
        const unsigned long long m = __ballot(h == n);
        if (h == n) pre = (int)__popcll(m & lt);
        if (l == 0) wcnt[w][n] = (int)__popcll(m);
    }
    __syncthreads();
    if (h >= 0) {
        int off = hist[h];
        for (int w2 = 0; w2 < w; ++w2) off += wcnt[w2][h];
        lists[h * TOK_TOTAL + off + pre] = tok;
    }
    if (i == 31 && t < 16) {
        int tot = hist[t];
        #pragma unroll
        for (int w2 = 0; w2 < 4; ++w2) tot += wcnt[w2][t];
        counts[t] = tot;
    }
}

// --------------------------------------------------------------- mlp8 ----
// Combination of the three bracketed mechanisms (r9/r10/r11 post-mortems):
//   * 32-token tile -> halves B traffic per token (the L3-BW term);
//   * X hi-only (r10 PROVED absmax unchanged at 1.953e-3) -> funds the
//     bigger tile: A-LDS stays 32KB; total 66.5KB -> 2 blocks/CU;
//   * 8 waves x 32 cols, 2 token-halves per B-frag -> keeps 2 MFMA per
//     B-load (the latency-hiding density r10 proved essential) and
//     ~24% occupancy (same as r6).
// Fragment indexing: stage from mlp5, H-write/read from mlp7, B-offsets
// from mlp4 - all correctness-proven. unroll stays 4 (r7 lesson).
__global__ __launch_bounds__(512) void mth_mlp8(
    const float* __restrict__ X, const int* __restrict__ counts,
    const int* __restrict__ lists,
    const ushort* __restrict__ W1h, const ushort* __restrict__ W2h,
    const float* __restrict__ b1, const float* __restrict__ b2,
    const float* __restrict__ W3, const float* __restrict__ b3,
    float* __restrict__ out)
{
    __shared__ __align__(16) ushort Ah[16][2][64][8];   // 32 KB [kc][tf][lane][e]
    __shared__ __align__(16) ushort Hh[8][2][64][8];    // 16 KB
    __shared__ __align__(16) ushort Hl[8][2][64][8];    // 16 KB
    __shared__ float part[8][32][2];                    //  2 KB

    const int b = blockIdx.x;
    const int n = ((b & 7) << 1) | ((b >> 3) & 1);      // XCD-clustered heads
    const int tile0 = b >> 4;                            // 0..15, stride 16

    const int tid = threadIdx.x;
    const int w   = tid >> 6;      // wave 0..7: cols [32w, 32w+32)
    const int l   = tid & 63;
    const int r16 = l & 15;
    const int kg  = l >> 4;

    const int cnt = counts[n];
    const int listbase = n * TOK_TOTAL;

    float bias1[2], bias2[2];
    float2 w3v[2];
    #pragma unroll
    for (int cf = 0; cf < 2; ++cf) {
        const int col = w * 32 + cf * 16 + r16;
        bias1[cf] = b1[n * HDIM + col];
        bias2[cf] = b2[n * HDIM + col];
        w3v[cf]   = *(const float2*)(W3 + (size_t)(n * HDIM + col) * 2);
    }
    const ushort* w1hn = W1h + (size_t)n * (16 * 8192);
    const ushort* w2hn = W2h + (size_t)n * (8 * 8192);
    const int le8 = l * 8;                               // lane element offset

    for (int T = tile0; T * 32 < cnt; T += 16) {
        // ---- stage: 32 X rows (fp32 coalesced) -> hi-only fragments ----
        #pragma unroll
        for (int p = 0; p < 8; ++p) {
            const int q   = tid + p * 512;               // float4 slot 0..4095
            const int row = q >> 7;                      // 0..31
            const int f4  = q & 127;
            const int tokidx = min(T * 32 + row, cnt - 1);
            const int tok = lists[listbase + tokidx];
            const float4 f = *(const float4*)(X + (size_t)tok * DDIM + f4 * 4);
            const int kc  = f4 >> 3;
            const int kgw = (f4 >> 1) & 3;
            const int j0  = (f4 & 1) * 4;
            const int tfs = row >> 4;
            const int rs  = row & 15;
            const int ln2 = (kgw * 16 + rs) ^ (kc & 7);
            ushort4v hv;
            const float vv[4] = {f.x, f.y, f.z, f.w};
            #pragma unroll
            for (int e = 0; e < 4; ++e) hv[e] = f2bf(vv[e]);
            *(ushort4v*)&Ah[kc][tfs][ln2][j0] = hv;
        }
        __syncthreads();

        // ---- layer 1: h1 = relu(X W1 + b1); 2 MFMA per B-load (tf=0,1) ----
        f32x4 acc[2][2];                 // [tf][cf]
        #pragma unroll
        for (int tf = 0; tf < 2; ++tf)
            #pragma unroll
            for (int cf = 0; cf < 2; ++cf) acc[tf][cf] = (f32x4){0.f, 0.f, 0.f, 0.f};

        #pragma unroll 4
        for (int kc = 0; kc < 16; ++kc) {
            const int ls = l ^ (kc & 7);
            const short8 ah0 = *(const short8*)&Ah[kc][0][ls][0];
            const short8 ah1 = *(const short8*)&Ah[kc][1][ls][0];
            const ushort* bp = w1hn + kc * 8192 + le8;
            #pragma unroll
            for (int cf = 0; cf < 2; ++cf) {
                const short8 bh = *(const short8*)(bp + (w * 2 + cf) * 512);
                acc[0][cf] = __builtin_amdgcn_mfma_f32_16x16x32_bf16(ah0, bh, acc[0][cf], 0, 0, 0);
                acc[1][cf] = __builtin_amdgcn_mfma_f32_16x16x32_bf16(ah1, bh, acc[1][cf], 0, 0, 0);
            }
        }

        // ---- h1 -> LDS fragments (hi/lo); wave w owns k-slice kc2 = w ----
        #pragma unroll
        for (int tf = 0; tf < 2; ++tf) {
            #pragma unroll
            for (int cf = 0; cf < 2; ++cf) {
                const int lp = (cf * 2 + (r16 >> 3)) * 16;
                const int e  = r16 & 7;
                #pragma unroll
                for (int j = 0; j < 4; ++j) {
                    const float v = fmaxf(acc[tf][cf][j] + bias1[cf], 0.f);
                    const uint u = __float_as_uint(v);
                    Hh[w][tf][lp + kg * 4 + j][e] = (ushort)(u >> 16);
                    Hl[w][tf][lp + kg * 4 + j][e] =
                        f2bf(v - __uint_as_float(u & 0xffff0000u));
                }
            }
        }
        __syncthreads();

        // ---- layer 2: h2 = relu(h1 W2 + b2); 4 MFMA per B-load ----
        f32x4 acc2[2][2];
        #pragma unroll
        for (int tf = 0; tf < 2; ++tf)
            #pragma unroll
            for (int cf = 0; cf < 2; ++cf) acc2[tf][cf] = (f32x4){0.f, 0.f, 0.f, 0.f};

        #pragma unroll 4
        for (int kc = 0; kc < 8; ++kc) {
            const short8 ah0 = *(const short8*)&Hh[kc][0][l][0];
            const short8 al0 = *(const short8*)&Hl[kc][0][l][0];
            const short8 ah1 = *(const short8*)&Hh[kc][1][l][0];
            const short8 al1 = *(const short8*)&Hl[kc][1][l][0];
            const ushort* bp = w2hn + kc * 8192 + le8;
            #pragma unroll
            for (int cf = 0; cf < 2; ++cf) {
                const short8 bh = *(const short8*)(bp + (w * 2 + cf) * 512);
                acc2[0][cf] = __builtin_amdgcn_mfma_f32_16x16x32_bf16(ah0, bh, acc2[0][cf], 0, 0, 0);
                acc2[0][cf] = __builtin_amdgcn_mfma_f32_16x16x32_bf16(al0, bh, acc2[0][cf], 0, 0, 0);
                acc2[1][cf] = __builtin_amdgcn_mfma_f32_16x16x32_bf16(ah1, bh, acc2[1][cf], 0, 0, 0);
                acc2[1][cf] = __builtin_amdgcn_mfma_f32_16x16x32_bf16(al1, bh, acc2[1][cf], 0, 0, 0);
            }
        }

        // ---- layer 3: partial dot over this wave's 32 cols, both halves ----
        float p[2][4][2];
        #pragma unroll
        for (int tf = 0; tf < 2; ++tf)
            #pragma unroll
            for (int j = 0; j < 4; ++j) { p[tf][j][0] = 0.f; p[tf][j][1] = 0.f; }
        #pragma unroll
        for (int tf = 0; tf < 2; ++tf) {
            #pragma unroll
            for (int cf = 0; cf < 2; ++cf) {
                #pragma unroll
                for (int j = 0; j < 4; ++j) {
                    const float v = fmaxf(acc2[tf][cf][j] + bias2[cf], 0.f);
                    p[tf][j][0] = fmaf(v, w3v[cf].x, p[tf][j][0]);
                    p[tf][j][1] = fmaf(v, w3v[cf].y, p[tf][j][1]);
                }
            }
        }
        #pragma unroll
        for (int off = 8; off >= 1; off >>= 1) {
            #pragma unroll
            for (int tf = 0; tf < 2; ++tf)
                #pragma unroll
                for (int j = 0; j < 4; ++j) {
                    p[tf][j][0] += __shfl_xor(p[tf][j][0], off);
                    p[tf][j][1] += __shfl_xor(p[tf][j][1], off);
                }
        }
        if (r16 == 0) {
            #pragma unroll
            for (int tf = 0; tf < 2; ++tf)
                #pragma unroll
                for (int j = 0; j < 4; ++j) {
                    part[w][tf * 16 + kg * 4 + j][0] = p[tf][j][0];
                    part[w][tf * 16 + kg * 4 + j][1] = p[tf][j][1];
                }
        }
        __syncthreads();

        if (tid < 64) {
            const int tk = tid >> 1, o = tid & 1;        // token 0..31, out idx
            if (T * 32 + tk < cnt) {
                float s = 0.f;
                #pragma unroll
                for (int w2 = 0; w2 < 8; ++w2) s += part[w2][tk][o];
                const int tok = lists[listbase + T * 32 + tk];
                out[(size_t)tok * 2 + o] = s + b3[n * 2 + o];
            }
        }
        __syncthreads();
    }
}

// ------------------------------------------------- fallback (round 1) ----
#define CHUNKS 16
#define CHUNK (TOK_TOTAL / CHUNKS)
#define TILE 32
#define KB 16

__global__ __launch_bounds__(256) void mth_routed_fp32(
    const float* __restrict__ X, const int* __restrict__ tasks,
    const int* __restrict__ lut,
    const float* __restrict__ W1, const float* __restrict__ b1,
    const float* __restrict__ W2, const float* __restrict__ b2,
    const float* __restrict__ W3, const float* __restrict__ b3,
    float* __restrict__ out)
{
    const int n = blockIdx.x, chnk = blockIdx.y, tid = threadIdx.x;
    const int lane = tid & 63, wv = tid >> 6, tx = tid & 31, ty = tid >> 5;
    __shared__ int s_list[CHUNK];
    __shared__ int s_cnt[8];
    __shared__ __align__(16) float s_x[KB][TILE];
    __shared__ __align__(16) float s_w[KB][HDIM];
    __shared__ __align__(16) float s_h[HDIM][TILE];
    const int base = chnk * CHUNK;
    int mytok[2], mypre[2], myseg[2]; bool mymatch[2];
    #pragma unroll
    for (int i = 0; i < 2; ++i) {
        const int tok = base + i * 256 + tid;
        const int task = tasks[tok];
        const int hidx = (task >= 0 && task < VOCAB) ? lut[task] : -1;
        const bool match = (hidx == n);
        const unsigned long long mask = __ballot(match);
        mytok[i] = tok; mymatch[i] = match;
        mypre[i] = __popcll(mask & ((1ULL << lane) - 1ULL));
        myseg[i] = i * 4 + wv;
        if (lane == 0) s_cnt[i * 4 + wv] = (int)__popcll(mask);
    }
    __syncthreads();
    int total = 0; int myoff[2] = {0, 0};
    #pragma unroll
    for (int s2 = 0; s2 < 8; ++s2) {
        if (s2 == myseg[0]) myoff[0] = total;
        if (s2 == myseg[1]) myoff[1] = total;
        total += s_cnt[s2];
    }
    #pragma unroll
    for (int i = 0; i < 2; ++i)
        if (mymatch[i]) s_list[myoff[i] + mypre[i]] = mytok[i];
    __syncthreads();
    const int ntok = total;
    if (ntok == 0) return;
    float bias1[8], bias2[8];
    #pragma unroll
    for (int j = 0; j < 8; ++j) {
        bias1[j] = b1[n * HDIM + tx * 8 + j];
        bias2[j] = b2[n * HDIM + tx * 8 + j];
    }
    float w3v[16];
    #pragma unroll
    for (int j = 0; j < 16; ++j) w3v[j] = W3[n * HDIM * ODIM + tx * 8 * ODIM + j];
    const float b3v0 = b3[n * ODIM + 0], b3v1 = b3[n * ODIM + 1];
    const float* W1n = W1 + (size_t)n * DDIM * HDIM;
    const float* W2n = W2 + (size_t)n * HDIM * HDIM;
    for (int ts = 0; ts < ntok; ts += TILE) {
        const int m = min(TILE, ntok - ts);
        float acc[4][8];
        #pragma unroll
        for (int t = 0; t < 4; ++t)
            #pragma unroll
            for (int j = 0; j < 8; ++j) acc[t][j] = 0.f;
        for (int kc = 0; kc < DDIM / KB; ++kc) {
            const float4* src = (const float4*)(W1n + kc * KB * HDIM);
            float4* dst = (float4*)s_w;
            #pragma unroll
            for (int p = 0; p < 4; ++p) dst[tid + p * 256] = src[tid + p * 256];
            #pragma unroll
            for (int p = 0; p < 2; ++p) {
                const int e = tid + p * 256;
                const int dd = e >> 5, t = e & 31;
                float v = 0.f;
                if (t < m) v = X[(size_t)s_list[ts + t] * DDIM + kc * KB + dd];
                s_x[dd][t] = v;
            }
            __syncthreads();
            #pragma unroll
            for (int dd = 0; dd < KB; ++dd) {
                const float4 xa = *(const float4*)&s_x[dd][ty * 4];
                const float4 wa = *(const float4*)&s_w[dd][tx * 8];
                const float4 wb = *(const float4*)&s_w[dd][tx * 8 + 4];
                const float xs[4] = {xa.x, xa.y, xa.z, xa.w};
                const float ws[8] = {wa.x, wa.y, wa.z, wa.w, wb.x, wb.y, wb.z, wb.w};
                #pragma unroll
                for (int t = 0; t < 4; ++t)
                    #pragma unroll
                    for (int j = 0; j < 8; ++j) acc[t][j] = fmaf(xs[t], ws[j], acc[t][j]);
            }
            __syncthreads();
        }
        #pragma unroll
        for (int j = 0; j < 8; ++j) {
            float4 v;
            v.x = fmaxf(acc[0][j] + bias1[j], 0.f);
            v.y = fmaxf(acc[1][j] + bias1[j], 0.f);
            v.z = fmaxf(acc[2][j] + bias1[j], 0.f);
            v.w = fmaxf(acc[3][j] + bias1[j], 0.f);
            *(float4*)&s_h[tx * 8 + j][ty * 4] = v;
        }
        __syncthreads();
        float acc2[4][8];
        #pragma unroll
        for (int t = 0; t < 4; ++t)
            #pragma unroll
            for (int j = 0; j < 8; ++j) acc2[t][j] = 0.f;
        for (int kc = 0; kc < HDIM / KB; ++kc) {
            const float4* src = (const float4*)(W2n + kc * KB * HDIM);
            float4* dst = (float4*)s_w;
            #pragma unroll
            for (int p = 0; p < 4; ++p) dst[tid + p * 256] = src[tid + p * 256];
            __syncthreads();
            #pragma unroll
            for (int dd = 0; dd < KB; ++dd) {
                const int k = kc * KB + dd;
                const float4 xa = *(const float4*)&s_h[k][ty * 4];
                const float4 wa = *(const float4*)&s_w[dd][tx * 8];
                const float4 wb = *(const float4*)&s_w[dd][tx * 8 + 4];
                const float xs[4] = {xa.x, xa.y, xa.z, xa.w};
                const float ws[8] = {wa.x, wa.y, wa.z, wa.w, wb.x, wb.y, wb.z, wb.w};
                #pragma unroll
                for (int t = 0; t < 4; ++t)
                    #pragma unroll
                    for (int j = 0; j < 8; ++j) acc2[t][j] = fmaf(xs[t], ws[j], acc2[t][j]);
            }
            __syncthreads();
        }
        float p0[4] = {0.f, 0.f, 0.f, 0.f}, p1[4] = {0.f, 0.f, 0.f, 0.f};
        #pragma unroll
        for (int t = 0; t < 4; ++t)
            #pragma unroll
            for (int j = 0; j < 8; ++j) {
                const float v = fmaxf(acc2[t][j] + bias2[j], 0.f);
                p0[t] = fmaf(v, w3v[j * 2 + 0], p0[t]);
                p1[t] = fmaf(v, w3v[j * 2 + 1], p1[t]);
            }
        #pragma unroll
        for (int off = 16; off > 0; off >>= 1)
            #pragma unroll
            for (int t = 0; t < 4; ++t) {
                p0[t] += __shfl_xor(p0[t], off);
                p1[t] += __shfl_xor(p1[t], off);
            }
        if (tx == 0) {
            #pragma unroll
            for (int t = 0; t < 4; ++t) {
                const int ti = ty * 4 + t;
                if (ti < m) {
                    const int tok = s_list[ts + ti];
                    out[tok * ODIM + 0] = p0[t] + b3v0;
                    out[tok * ODIM + 1] = p1[t] + b3v1;
                }
            }
        }
        __syncthreads();
    }
}

// -------------------------------------------------------------- launch ----
extern "C" void kernel_launch(void* const* d_in, const int* in_sizes, int n_in,
                              void* d_out, int out_size, void* d_ws, size_t ws_size,
                              hipStream_t stream) {
    (void)in_sizes; (void)n_in;
    const float* X     = (const float*)d_in[0];
    const int*   tasks = (const int*)d_in[1];
    const int*   lut   = (const int*)d_in[2];
    const float* W1    = (const float*)d_in[3];
    const float* b1    = (const float*)d_in[4];
    const float* W2    = (const float*)d_in[5];
    const float* b2    = (const float*)d_in[6];
    const float* W3    = (const float*)d_in[7];
    const float* b3    = (const float*)d_in[8];
    float* out = (float*)d_out;

    const size_t OFF_COUNTS = 0;
    const size_t OFF_LISTS  = 64;
    const size_t OFF_W1H    = OFF_LISTS + (size_t)NHEADS * TOK_TOTAL * 4;
    const size_t NW1        = (size_t)NHEADS * DDIM * HDIM;   // 2M elems
    const size_t NW2        = (size_t)NHEADS * HDIM * HDIM;   // 1M elems
    const size_t OFF_W2H    = OFF_W1H + NW1 * 2;
    const size_t NEED       = OFF_W2H + NW2 * 2;              // ~6.8 MB

    if (ws_size < NEED) {
        hipMemsetAsync(out, 0, (size_t)out_size * sizeof(float), stream);
        dim3 grid(NHEADS, CHUNKS);
        mth_routed_fp32<<<grid, 256, 0, stream>>>(X, tasks, lut, W1, b1, W2, b2, W3, b3, out);
        return;
    }

    char* ws = (char*)d_ws;
    int*    counts = (int*)(ws + OFF_COUNTS);
    int*    lists  = (int*)(ws + OFF_LISTS);
    ushort* W1h    = (ushort*)(ws + OFF_W1H);
    ushort* W2h    = (ushort*)(ws + OFF_W2H);

    mth_prep_route<<<416, 256, 0, stream>>>(W1, W2, tasks, lut,
                                            W1h, W2h, counts, lists, out);
    mth_mlp8<<<256, 512, 0, stream>>>(X, counts, lists, W1h, W2h,
                                      b1, b2, W3, b3, out);
}

// Round 14
// 33.980 us; speedup vs baseline: 1.1705x; 1.1705x over previous
//
#include <hip/hip_runtime.h>

#define TOK_TOTAL 8192
#define DDIM 512
#define HDIM 256
#define ODIM 2
#define NHEADS 16
#define VOCAB 1024

typedef __attribute__((ext_vector_type(8))) short short8;
typedef __attribute__((ext_vector_type(4))) float f32x4;
typedef __attribute__((ext_vector_type(4))) unsigned short ushort4v;

__device__ inline ushort f2bf(float f) {           // RNE fp32->bf16
    uint u = __float_as_uint(f);
    uint r = (u + 0x7fffu + ((u >> 16) & 1u)) >> 16;
    return (ushort)r;
}
__device__ inline float bf2f(ushort h) { return __uint_as_float(((uint)h) << 16); }

// ---------------------------------------------------------- prep+route ----
// FINAL: proven r6 configuration (33.9us; reproduced 34.8us r12).
// Bracketing experiments, each a single variable, ALL regressed:
//   r7  unroll 4->8            58.5us (VGPR 68->132, occupancy 20->7%)
//   r8  atomic->ballot routing 42.2us (ballots serialize the scan)
//   r9  16->32-token tile      41.9us (97KB LDS -> 1 block/CU)
//   r10 drop X-lo              52.8us (lost 2-MFMA-per-load latency hiding)
//   r11 4->8 wave col-split    37.3us (TLP wash, more barriers)
//   r13 32-tile+hi-only combo  39.8us (serial chain per tile dominates)
// Blocks [0,384): W1/W2 fp32 -> single bf16(RNE) plane per (n,kc) in
//   LANE-MONOTONIC fragment order: slot = cg*512 + lane*8 + j holds element
//   (k = kc*32 + (lane>>4)*8 + j, c = cg*16 + (lane&15)) -> a wave's B-frag
//   load is one contiguous 1KB read (base + lane*16B). This layout was the
//   big win (r5->r6: 66->34us); scattered fragment order ran at ~14B/cy/CU.
// Blocks [384,416): routing with LDS-atomic histogram prefix.
__global__ __launch_bounds__(256) void mth_prep_route(
    const float* __restrict__ W1, const float* __restrict__ W2,
    const int* __restrict__ tasks, const int* __restrict__ lut,
    ushort* __restrict__ W1h, ushort* __restrict__ W2h,
    int* __restrict__ counts, int* __restrict__ lists,
    float* __restrict__ out)
{
    const int b = blockIdx.x, t = threadIdx.x;

    if (b < 384) {                       // ---------------- W split ----------
        __shared__ float s[32][257];
        const float* src;
        ushort* dh;
        if (b < 256) {
            const int n = b >> 4, kc = b & 15;
            src = W1 + (size_t)(n * 16 + kc) * 8192;
            dh  = W1h + (size_t)(n * 16 + kc) * 8192;
        } else {
            const int b2 = b - 256, n = b2 >> 3, kc = b2 & 7;
            src = W2 + (size_t)(n * 8 + kc) * 8192;
            dh  = W2h + (size_t)(n * 8 + kc) * 8192;
        }
        #pragma unroll
        for (int i = 0; i < 8; ++i) {
            const int q = t + i * 256;
            const float4 f = ((const float4*)src)[q];
            const int k = q >> 6, c4 = (q & 63) * 4;
            s[k][c4] = f.x; s[k][c4 + 1] = f.y; s[k][c4 + 2] = f.z; s[k][c4 + 3] = f.w;
        }
        __syncthreads();
        #pragma unroll
        for (int i = 0; i < 4; ++i) {
            const int s8 = t + i * 256;          // short8 slot, monotonic
            const int lidx = s8 & 63;
            const int c = (s8 >> 6) * 16 + (lidx & 15);
            const int kw = (lidx >> 4) * 8;
            short8 hb;
            #pragma unroll
            for (int j = 0; j < 8; ++j) hb[j] = (short)f2bf(s[kw + j][c]);
            *(short8*)(dh + (size_t)s8 * 8) = hb;
        }
        return;
    }

    // ---------------- routing (atomic histogram prefix) ----------------
    const int i = b - 384;               // chunk 0..31
    __shared__ int hist[16];             // counts in chunks < i
    __shared__ int wcnt[4][16];          // per-wave counts in own chunk
    if (t < 16) hist[t] = 0;
    __syncthreads();
    for (int q = t; q < i * 256; q += 256) {
        const int task = tasks[q];
        const int h = (task >= 0 && task < VOCAB) ? lut[task] : -1;
        if (h >= 0) atomicAdd(&hist[h], 1);
    }
    const int tok = i * 256 + t;
    const int task = tasks[tok];
    const int h = (task >= 0 && task < VOCAB) ? lut[task] : -1;
    if (h < 0) {
        out[(size_t)tok * 2]     = 0.f;
        out[(size_t)tok * 2 + 1] = 0.f;
    }
    const int w = t >> 6, l = t & 63;
    const unsigned long long lt = (1ULL << l) - 1ULL;
    int pre = 0;
    #pragma unroll
    for (int n = 0; n < NHEADS; ++n) {
        const unsigned long long m = __ballot(h == n);
        if (h == n) pre = (int)__popcll(m & lt);
        if (l == 0) wcnt[w][n] = (int)__popcll(m);
    }
    __syncthreads();
    if (h >= 0) {
        int off = hist[h];
        for (int w2 = 0; w2 < w; ++w2) off += wcnt[w2][h];
        lists[h * TOK_TOTAL + off + pre] = tok;
    }
    if (i == 31 && t < 16) {
        int tot = hist[t];
        #pragma unroll
        for (int w2 = 0; w2 < 4; ++w2) tot += wcnt[w2][t];
        counts[t] = tot;
    }
}

// --------------------------------------------------------------- mlp4 ----
// 16-token tiles, 4 waves/block; wave w owns cols [64w, 64w+64).
// B: lane-monotonic fragment planes (1KB contiguous wave loads), bf16 hi only.
// A: X staged fp32 -> hi/lo LDS fragments (XOR-swizzled by kc for writes).
// The al-MFMA doubles as latency-hiding work (2 MFMA per B-load) - removing
// it regressed 41% (r10). kc-loop unroll MUST stay 4 (r7: unroll 8 ->
// VGPR 68->132, occupancy 20%->7%, +30us).
__global__ __launch_bounds__(256) void mth_mlp4(
    const float* __restrict__ X, const int* __restrict__ counts,
    const int* __restrict__ lists,
    const ushort* __restrict__ W1h, const ushort* __restrict__ W2h,
    const float* __restrict__ b1, const float* __restrict__ b2,
    const float* __restrict__ W3, const float* __restrict__ b3,
    float* __restrict__ out)
{
    __shared__ __align__(16) ushort Ah[16][64][8];   // 16 KB
    __shared__ __align__(16) ushort Al[16][64][8];   // 16 KB
    __shared__ __align__(16) ushort Hh[8][64][8];    //  8 KB
    __shared__ __align__(16) ushort Hl[8][64][8];    //  8 KB
    __shared__ float part[4][16][2];

    const int b = blockIdx.x;
    const int n = ((b & 7) << 1) | ((b >> 3) & 1);   // XCD-clustered heads
    const int tile0 = b >> 4;                         // 0..63, stride 64

    const int tid = threadIdx.x;
    const int w   = tid >> 6;
    const int l   = tid & 63;
    const int r16 = l & 15;
    const int kg  = l >> 4;

    const int cnt = counts[n];
    const int listbase = n * TOK_TOTAL;

    float bias1[4], bias2[4];
    float2 w3v[4];
    #pragma unroll
    for (int cf = 0; cf < 4; ++cf) {
        const int col = w * 64 + cf * 16 + r16;
        bias1[cf] = b1[n * HDIM + col];
        bias2[cf] = b2[n * HDIM + col];
        w3v[cf]   = *(const float2*)(W3 + (size_t)(n * HDIM + col) * 2);
    }
    const ushort* w1hn = W1h + (size_t)n * (16 * 8192);
    const ushort* w2hn = W2h + (size_t)n * (8 * 8192);
    const int le8 = l * 8;                            // lane element offset

    for (int T = tile0; T * 16 < cnt; T += 64) {
        // ---- stage: 16 X rows (fp32, contiguous 1KB wave reads) -> frags --
        #pragma unroll
        for (int p = 0; p < 8; ++p) {
            const int q   = tid + p * 256;            // float4 slot 0..2047
            const int row = q >> 7;
            const int f4  = q & 127;
            const int tokidx = min(T * 16 + row, cnt - 1);
            const int tok = lists[listbase + tokidx];
            const float4 f = *(const float4*)(X + (size_t)tok * DDIM + f4 * 4);
            const int kc  = f4 >> 3;
            const int kgw = (f4 >> 1) & 3;
            const int j0  = (f4 & 1) * 4;
            const int ln2 = (kgw * 16 + row) ^ (kc & 7);
            ushort4v hv, lv;
            const float vv[4] = {f.x, f.y, f.z, f.w};
            #pragma unroll
            for (int e = 0; e < 4; ++e) {
                const uint u = __float_as_uint(vv[e]);
                hv[e] = (ushort)(u >> 16);
                lv[e] = f2bf(vv[e] - __uint_as_float(u & 0xffff0000u));
            }
            *(ushort4v*)&Ah[kc][ln2][j0] = hv;
            *(ushort4v*)&Al[kc][ln2][j0] = lv;
        }
        __syncthreads();

        // ---- layer 1: h1 = relu(X W1 + b1) ----
        f32x4 acc[4];
        #pragma unroll
        for (int cf = 0; cf < 4; ++cf) acc[cf] = (f32x4){0.f, 0.f, 0.f, 0.f};

        #pragma unroll 4
        for (int kc = 0; kc < 16; ++kc) {
            const int ls = l ^ (kc & 7);
            const short8 ah = *(const short8*)&Ah[kc][ls][0];
            const short8 al = *(const short8*)&Al[kc][ls][0];
            const ushort* bp = w1hn + kc * 8192 + le8;
            #pragma unroll
            for (int cf = 0; cf < 4; ++cf) {
                const short8 bh = *(const short8*)(bp + (w * 4 + cf) * 512);
                acc[cf] = __builtin_amdgcn_mfma_f32_16x16x32_bf16(ah, bh, acc[cf], 0, 0, 0);
                acc[cf] = __builtin_amdgcn_mfma_f32_16x16x32_bf16(al, bh, acc[cf], 0, 0, 0);
            }
        }

        // ---- h1 -> LDS fragments (hi/lo), wave w owns kc2 in {2w,2w+1} ----
        #pragma unroll
        for (int cf = 0; cf < 4; ++cf) {
            const int kc2 = 2 * w + (cf >> 1);
            const int lp  = ((cf & 1) * 2 + (r16 >> 3)) * 16;
            const int e   = r16 & 7;
            #pragma unroll
            for (int j = 0; j < 4; ++j) {
                const float v = fmaxf(acc[cf][j] + bias1[cf], 0.f);
                const uint u = __float_as_uint(v);
                Hh[kc2][lp + kg * 4 + j][e] = (ushort)(u >> 16);
                Hl[kc2][lp + kg * 4 + j][e] =
                    f2bf(v - __uint_as_float(u & 0xffff0000u));
            }
        }
        __syncthreads();

        // ---- layer 2: h2 = relu(h1 W2 + b2) ----
        f32x4 acc2[4];
        #pragma unroll
        for (int cf = 0; cf < 4; ++cf) acc2[cf] = (f32x4){0.f, 0.f, 0.f, 0.f};

        #pragma unroll 4
        for (int kc = 0; kc < 8; ++kc) {
            const short8 ah = *(const short8*)&Hh[kc][l][0];
            const short8 al = *(const short8*)&Hl[kc][l][0];
            const ushort* bp = w2hn + kc * 8192 + le8;
            #pragma unroll
            for (int cf = 0; cf < 4; ++cf) {
                const short8 bh = *(const short8*)(bp + (w * 4 + cf) * 512);
                acc2[cf] = __builtin_amdgcn_mfma_f32_16x16x32_bf16(ah, bh, acc2[cf], 0, 0, 0);
                acc2[cf] = __builtin_amdgcn_mfma_f32_16x16x32_bf16(al, bh, acc2[cf], 0, 0, 0);
            }
        }

        // ---- layer 3: partial dot over this wave's 64 cols ----
        float p[4][2];
        #pragma unroll
        for (int j = 0; j < 4; ++j) { p[j][0] = 0.f; p[j][1] = 0.f; }
        #pragma unroll
        for (int cf = 0; cf < 4; ++cf) {
            #pragma unroll
            for (int j = 0; j < 4; ++j) {
                const float v = fmaxf(acc2[cf][j] + bias2[cf], 0.f);
                p[j][0] = fmaf(v, w3v[cf].x, p[j][0]);
                p[j][1] = fmaf(v, w3v[cf].y, p[j][1]);
            }
        }
        #pragma unroll
        for (int off = 8; off >= 1; off >>= 1) {
            #pragma unroll
            for (int j = 0; j < 4; ++j) {
                p[j][0] += __shfl_xor(p[j][0], off);
                p[j][1] += __shfl_xor(p[j][1], off);
            }
        }
        if (r16 == 0) {
            #pragma unroll
            for (int j = 0; j < 4; ++j) {
                part[w][kg * 4 + j][0] = p[j][0];
                part[w][kg * 4 + j][1] = p[j][1];
            }
        }
        __syncthreads();

        if (tid < 32) {
            const int tk = tid >> 1, o = tid & 1;
            if (T * 16 + tk < cnt) {
                const float s = part[0][tk][o] + part[1][tk][o] +
                                part[2][tk][o] + part[3][tk][o];
                const int tok = lists[listbase + T * 16 + tk];
                out[(size_t)tok * 2 + o] = s + b3[n * 2 + o];
            }
        }
        __syncthreads();
    }
}

// ------------------------------------------------- fallback (round 1) ----
#define CHUNKS 16
#define CHUNK (TOK_TOTAL / CHUNKS)
#define TILE 32
#define KB 16

__global__ __launch_bounds__(256) void mth_routed_fp32(
    const float* __restrict__ X, const int* __restrict__ tasks,
    const int* __restrict__ lut,
    const float* __restrict__ W1, const float* __restrict__ b1,
    const float* __restrict__ W2, const float* __restrict__ b2,
    const float* __restrict__ W3, const float* __restrict__ b3,
    float* __restrict__ out)
{
    const int n = blockIdx.x, chnk = blockIdx.y, tid = threadIdx.x;
    const int lane = tid & 63, wv = tid >> 6, tx = tid & 31, ty = tid >> 5;
    __shared__ int s_list[CHUNK];
    __shared__ int s_cnt[8];
    __shared__ __align__(16) float s_x[KB][TILE];
    __shared__ __align__(16) float s_w[KB][HDIM];
    __shared__ __align__(16) float s_h[HDIM][TILE];
    const int base = chnk * CHUNK;
    int mytok[2], mypre[2], myseg[2]; bool mymatch[2];
    #pragma unroll
    for (int i = 0; i < 2; ++i) {
        const int tok = base + i * 256 + tid;
        const int task = tasks[tok];
        const int hidx = (task >= 0 && task < VOCAB) ? lut[task] : -1;
        const bool match = (hidx == n);
        const unsigned long long mask = __ballot(match);
        mytok[i] = tok; mymatch[i] = match;
        mypre[i] = __popcll(mask & ((1ULL << lane) - 1ULL));
        myseg[i] = i * 4 + wv;
        if (lane == 0) s_cnt[i * 4 + wv] = (int)__popcll(mask);
    }
    __syncthreads();
    int total = 0; int myoff[2] = {0, 0};
    #pragma unroll
    for (int s2 = 0; s2 < 8; ++s2) {
        if (s2 == myseg[0]) myoff[0] = total;
        if (s2 == myseg[1]) myoff[1] = total;
        total += s_cnt[s2];
    }
    #pragma unroll
    for (int i = 0; i < 2; ++i)
        if (mymatch[i]) s_list[myoff[i] + mypre[i]] = mytok[i];
    __syncthreads();
    const int ntok = total;
    if (ntok == 0) return;
    float bias1[8], bias2[8];
    #pragma unroll
    for (int j = 0; j < 8; ++j) {
        bias1[j] = b1[n * HDIM + tx * 8 + j];
        bias2[j] = b2[n * HDIM + tx * 8 + j];
    }
    float w3v[16];
    #pragma unroll
    for (int j = 0; j < 16; ++j) w3v[j] = W3[n * HDIM * ODIM + tx * 8 * ODIM + j];
    const float b3v0 = b3[n * ODIM + 0], b3v1 = b3[n * ODIM + 1];
    const float* W1n = W1 + (size_t)n * DDIM * HDIM;
    const float* W2n = W2 + (size_t)n * HDIM * HDIM;
    for (int ts = 0; ts < ntok; ts += TILE) {
        const int m = min(TILE, ntok - ts);
        float acc[4][8];
        #pragma unroll
        for (int t = 0; t < 4; ++t)
            #pragma unroll
            for (int j = 0; j < 8; ++j) acc[t][j] = 0.f;
        for (int kc = 0; kc < DDIM / KB; ++kc) {
            const float4* src = (const float4*)(W1n + kc * KB * HDIM);
            float4* dst = (float4*)s_w;
            #pragma unroll
            for (int p = 0; p < 4; ++p) dst[tid + p * 256] = src[tid + p * 256];
            #pragma unroll
            for (int p = 0; p < 2; ++p) {
                const int e = tid + p * 256;
                const int dd = e >> 5, t = e & 31;
                float v = 0.f;
                if (t < m) v = X[(size_t)s_list[ts + t] * DDIM + kc * KB + dd];
                s_x[dd][t] = v;
            }
            __syncthreads();
            #pragma unroll
            for (int dd = 0; dd < KB; ++dd) {
                const float4 xa = *(const float4*)&s_x[dd][ty * 4];
                const float4 wa = *(const float4*)&s_w[dd][tx * 8];
                const float4 wb = *(const float4*)&s_w[dd][tx * 8 + 4];
                const float xs[4] = {xa.x, xa.y, xa.z, xa.w};
                const float ws[8] = {wa.x, wa.y, wa.z, wa.w, wb.x, wb.y, wb.z, wb.w};
                #pragma unroll
                for (int t = 0; t < 4; ++t)
                    #pragma unroll
                    for (int j = 0; j < 8; ++j) acc[t][j] = fmaf(xs[t], ws[j], acc[t][j]);
            }
            __syncthreads();
        }
        #pragma unroll
        for (int j = 0; j < 8; ++j) {
            float4 v;
            v.x = fmaxf(acc[0][j] + bias1[j], 0.f);
            v.y = fmaxf(acc[1][j] + bias1[j], 0.f);
            v.z = fmaxf(acc[2][j] + bias1[j], 0.f);
            v.w = fmaxf(acc[3][j] + bias1[j], 0.f);
            *(float4*)&s_h[tx * 8 + j][ty * 4] = v;
        }
        __syncthreads();
        float acc2[4][8];
        #pragma unroll
        for (int t = 0; t < 4; ++t)
            #pragma unroll
            for (int j = 0; j < 8; ++j) acc2[t][j] = 0.f;
        for (int kc = 0; kc < HDIM / KB; ++kc) {
            const float4* src = (const float4*)(W2n + kc * KB * HDIM);
            float4* dst = (float4*)s_w;
            #pragma unroll
            for (int p = 0; p < 4; ++p) dst[tid + p * 256] = src[tid + p * 256];
            __syncthreads();
            #pragma unroll
            for (int dd = 0; dd < KB; ++dd) {
                const int k = kc * KB + dd;
                const float4 xa = *(const float4*)&s_h[k][ty * 4];
                const float4 wa = *(const float4*)&s_w[dd][tx * 8];
                const float4 wb = *(const float4*)&s_w[dd][tx * 8 + 4];
                const float xs[4] = {xa.x, xa.y, xa.z, xa.w};
                const float ws[8] = {wa.x, wa.y, wa.z, wa.w, wb.x, wb.y, wb.z, wb.w};
                #pragma unroll
                for (int t = 0; t < 4; ++t)
                    #pragma unroll
                    for (int j = 0; j < 8; ++j) acc2[t][j] = fmaf(xs[t], ws[j], acc2[t][j]);
            }
            __syncthreads();
        }
        float p0[4] = {0.f, 0.f, 0.f, 0.f}, p1[4] = {0.f, 0.f, 0.f, 0.f};
        #pragma unroll
        for (int t = 0; t < 4; ++t)
            #pragma unroll
            for (int j = 0; j < 8; ++j) {
                const float v = fmaxf(acc2[t][j] + bias2[j], 0.f);
                p0[t] = fmaf(v, w3v[j * 2 + 0], p0[t]);
                p1[t] = fmaf(v, w3v[j * 2 + 1], p1[t]);
            }
        #pragma unroll
        for (int off = 16; off > 0; off >>= 1)
            #pragma unroll
            for (int t = 0; t < 4; ++t) {
                p0[t] += __shfl_xor(p0[t], off);
                p1[t] += __shfl_xor(p1[t], off);
            }
        if (tx == 0) {
            #pragma unroll
            for (int t = 0; t < 4; ++t) {
                const int ti = ty * 4 + t;
                if (ti < m) {
                    const int tok = s_list[ts + ti];
                    out[tok * ODIM + 0] = p0[t] + b3v0;
                    out[tok * ODIM + 1] = p1[t] + b3v1;
                }
            }
        }
        __syncthreads();
    }
}

// -------------------------------------------------------------- launch ----
extern "C" void kernel_launch(void* const* d_in, const int* in_sizes, int n_in,
                              void* d_out, int out_size, void* d_ws, size_t ws_size,
                              hipStream_t stream) {
    (void)in_sizes; (void)n_in;
    const float* X     = (const float*)d_in[0];
    const int*   tasks = (const int*)d_in[1];
    const int*   lut   = (const int*)d_in[2];
    const float* W1    = (const float*)d_in[3];
    const float* b1    = (const float*)d_in[4];
    const float* W2    = (const float*)d_in[5];
    const float* b2    = (const float*)d_in[6];
    const float* W3    = (const float*)d_in[7];
    const float* b3    = (const float*)d_in[8];
    float* out = (float*)d_out;

    const size_t OFF_COUNTS = 0;
    const size_t OFF_LISTS  = 64;
    const size_t OFF_W1H    = OFF_LISTS + (size_t)NHEADS * TOK_TOTAL * 4;
    const size_t NW1        = (size_t)NHEADS * DDIM * HDIM;   // 2M elems
    const size_t NW2        = (size_t)NHEADS * HDIM * HDIM;   // 1M elems
    const size_t OFF_W2H    = OFF_W1H + NW1 * 2;
    const size_t NEED       = OFF_W2H + NW2 * 2;              // ~6.8 MB

    if (ws_size < NEED) {
        hipMemsetAsync(out, 0, (size_t)out_size * sizeof(float), stream);
        dim3 grid(NHEADS, CHUNKS);
        mth_routed_fp32<<<grid, 256, 0, stream>>>(X, tasks, lut, W1, b1, W2, b2, W3, b3, out);
        return;
    }

    char* ws = (char*)d_ws;
    int*    counts = (int*)(ws + OFF_COUNTS);
    int*    lists  = (int*)(ws + OFF_LISTS);
    ushort* W1h    = (ushort*)(ws + OFF_W1H);
    ushort* W2h    = (ushort*)(ws + OFF_W2H);

    mth_prep_route<<<416, 256, 0, stream>>>(W1, W2, tasks, lut,
                                            W1h, W2h, counts, lists, out);
    mth_mlp4<<<1024, 256, 0, stream>>>(X, counts, lists, W1h, W2h,
                                       b1, b2, W3, b3, out);
}